// Round 8
// baseline (344.658 us; speedup 1.0000x reference)
//
#include <hip/hip_runtime.h>
#include <hip/hip_bf16.h>

// Problem constants (B=8192, IN=H=1024)
#define BATCH 8192
#define HDIM  1024
#define KDIM  2048   // IN + H concatenated
#define NDIM  4096   // 4*H

__device__ inline unsigned short f2bf(float x) {
    unsigned int u = __float_as_uint(x);
    unsigned int r = (u + 0x7fffu + ((u >> 16) & 1u)) >> 16;
    return (unsigned short)r;
}
__device__ inline float bf2f(unsigned short u) {
    return __uint_as_float((unsigned int)u << 16);
}

typedef __attribute__((ext_vector_type(8))) unsigned short us8;

// Merged converter v2: 8 elems/thread, 16B stores (full-line coalescing).
//  Wb [4096,2048] bf16: row n = [w_i[n] | w_h[n]], w_i half zeroed for rows
//  2048..3071 (chunk i_gc of gi is unused by the reference).
//  Xb [8192,2048] bf16: row r = [input[r] | h_prev[r]]
// R8/R9 localization: convert <= ~61us (never surfaced in top-5).
__global__ __launch_bounds__(256) void convert_kernel(
    const float* __restrict__ wi, const float* __restrict__ wh,
    const float* __restrict__ input, const float* __restrict__ h_prev,
    unsigned short* __restrict__ Wb, unsigned short* __restrict__ Xb)
{
    int idx = blockIdx.x * 256 + threadIdx.x;
    const int NW = NDIM * 256;              // weight 8-elem groups per matrix
    float4 v0, v1;
    unsigned short* dst;
    if (idx < NW) {
        int n = idx >> 8;
        int k = (idx & 255) << 3;
        if (k < 1024) {
            if (n >= 2048 && n < 3072) {
                v0 = make_float4(0.f, 0.f, 0.f, 0.f);
                v1 = v0;
            } else {
                v0 = *(const float4*)(wi + (size_t)n * 1024 + k);
                v1 = *(const float4*)(wi + (size_t)n * 1024 + k + 4);
            }
        } else {
            v0 = *(const float4*)(wh + (size_t)n * 1024 + (k - 1024));
            v1 = *(const float4*)(wh + (size_t)n * 1024 + (k - 1024) + 4);
        }
        dst = Wb + (size_t)n * KDIM + k;
    } else {
        int j = idx - NW;
        int r = j >> 8;
        int k = (j & 255) << 3;
        if (k < 1024) {
            v0 = *(const float4*)(input + (size_t)r * 1024 + k);
            v1 = *(const float4*)(input + (size_t)r * 1024 + k + 4);
        } else {
            v0 = *(const float4*)(h_prev + (size_t)r * 1024 + (k - 1024));
            v1 = *(const float4*)(h_prev + (size_t)r * 1024 + (k - 1024) + 4);
        }
        dst = Xb + (size_t)r * KDIM + k;
    }
    us8 o;
    o[0] = f2bf(v0.x); o[1] = f2bf(v0.y); o[2] = f2bf(v0.z); o[3] = f2bf(v0.w);
    o[4] = f2bf(v1.x); o[5] = f2bf(v1.y); o[6] = f2bf(v1.z); o[7] = f2bf(v1.w);
    *(us8*)dst = o;
}

// ---------------------------------------------------------------------------
// GEMM R12: m201-style 8-phase 256x256 schedule, R11 race FIXED.
// R11 bug: staged halves were contiguous row blocks (A0=rows 0-127), but
// read quadrants are per-wave unions (m0 = rows 0-63 u 128-191). P3's stage
// of (t+2).A1 overwrote rows 128-191 still re-read as "A0" in P4 (same for
// B n1 rows vs P2's B0 stage) -> absmax 1.58. Fix: stage-region == read-
// quadrant-region:
//   A half h: rows (wave>>2)*128 + h*64 + (wave&3)*16 + p*8
//   B half h: rows (wave>>1)*64  + h*32 + (wave&1)*16 + p*8
// Row bases stay 8-aligned -> swizzle (chunk p ^ (row&7)) and linear
// gload_lds dest unchanged; per-thread load counts unchanged -> vmcnt(6)
// induction unchanged.
// Schedule (verified accounting): per K-tile 4 phases, each {ds_reads of one
// C-quadrant || stage ONE half-tile -> BAR -> 16 MFMA (setprio) -> BAR}.
// Stage order: P1->(t+1).A0 (other buf), P2->(t+2).B0, P3->(t+2).A1,
// P4->(t+2).B1 + vmcnt(6) (forces all of tile t+1; leaves t+2's 3 halves in
// flight; every waited load issued >=3 phases earlier). Hazard check with
// fixed mapping: each staged region's last reader finished one barrier
// before the stage issue; P4's A0 re-read region untouched in iter t.
// ---------------------------------------------------------------------------
#define BM 256
#define BN 256
#define BK 64    // bf16 elems per row; 128 B

typedef __attribute__((ext_vector_type(8))) short bf16x8;
typedef __attribute__((ext_vector_type(4))) float f32x4;

#define PHASE_BAR() { asm volatile("" ::: "memory"); \
                      __builtin_amdgcn_s_barrier();  \
                      asm volatile("" ::: "memory"); }

// Stage the A-rows read as quadrant (mh) by all waves, for K-tile kt.
#define STAGE_HALF_A(b, h, kt)                                                 \
  { _Pragma("unroll") for (int p = 0; p < 2; ++p) {                            \
      const int rbase = (wave >> 2) * 128 + (h) * 64 + (wave & 3) * 16 + p * 8;\
      __builtin_amdgcn_global_load_lds(                                        \
        (const __attribute__((address_space(1))) void*)(                       \
            A + (size_t)(bm + rbase + srow) * KDIM + k0 + (kt) * BK + c_sw * 8),\
        (__attribute__((address_space(3))) void*)&As[b][rbase * BK], 16, 0, 0);\
  } }
// Stage the B-rows read as quadrant (nh) by all waves, for K-tile kt.
#define STAGE_HALF_B(b, h, kt)                                                 \
  { _Pragma("unroll") for (int p = 0; p < 2; ++p) {                            \
      const int rbase = (wave >> 1) * 64 + (h) * 32 + (wave & 1) * 16 + p * 8; \
      __builtin_amdgcn_global_load_lds(                                        \
        (const __attribute__((address_space(1))) void*)(                       \
            Bw + (size_t)(bn + rbase + srow) * KDIM + k0 + (kt) * BK + c_sw * 8),\
        (__attribute__((address_space(3))) void*)&Bs[b][rbase * BK], 16, 0, 0);\
  } }

// ds_read fragment groups (R4-verified layout: chunk = cbase ^ (row&7)).
#define READ_A4(buf, dst, mh)                                                  \
  { _Pragma("unroll") for (int i = 0; i < 4; ++i)                              \
    _Pragma("unroll") for (int kk = 0; kk < 2; ++kk) {                         \
      const int ra = wm + (mh) * 64 + i * 16 + ln15;                           \
      dst[i][kk] = *(const bf16x8*)                                            \
          &As[buf][ra * BK + (((kk * 4 + l16) ^ (ra & 7)) * 8)]; } }
#define READ_B2(buf, dst, nh)                                                  \
  { _Pragma("unroll") for (int j = 0; j < 2; ++j)                              \
    _Pragma("unroll") for (int kk = 0; kk < 2; ++kk) {                         \
      const int rb = wn + (nh) * 32 + j * 16 + ln15;                           \
      dst[j][kk] = *(const bf16x8*)                                            \
          &Bs[buf][rb * BK + (((kk * 4 + l16) ^ (rb & 7)) * 8)]; } }

// One C-quadrant: 4m x 2n fragments x 2 kk = 16 MFMA.
#define MFMA_Q(mh, nh, av, bv)                                                 \
  { __builtin_amdgcn_s_setprio(1);                                             \
    _Pragma("unroll") for (int i = 0; i < 4; ++i)                              \
    _Pragma("unroll") for (int j = 0; j < 2; ++j)                              \
    _Pragma("unroll") for (int kk = 0; kk < 2; ++kk)                           \
      acc[(mh) * 4 + i][(nh) * 2 + j] =                                        \
          __builtin_amdgcn_mfma_f32_16x16x32_bf16(                             \
              av[i][kk], bv[j][kk], acc[(mh) * 4 + i][(nh) * 2 + j], 0, 0, 0); \
    __builtin_amdgcn_s_setprio(0); }

__global__ __launch_bounds__(512) void gemm_bt_kernel(
    const unsigned short* __restrict__ A,
    const unsigned short* __restrict__ Bw,
    unsigned short* __restrict__ G,
    int M)
{
    __shared__ unsigned short As[2][BM * BK];   // 2 x 32 KB
    __shared__ unsigned short Bs[2][BN * BK];   // 2 x 32 KB  (128 KB total)

    const int tid  = threadIdx.x;
    const int lane = tid & 63;
    const int wave = tid >> 6;               // 0..7

    const int bid = blockIdx.x;              // n-fastest linear
    const int bm  = (bid >> 4) * BM;
    const int bn  = (bid & 15) * BN;

    const int wm = (wave >> 2) * 128;        // 0,128
    const int wn = (wave & 3) * 64;          // 0,64,128,192

    const int srow = lane >> 3;              // 0..7
    const int c_sw = (lane & 7) ^ srow;      // global 16B-chunk to fetch

    const int ln15 = lane & 15;
    const int l16  = lane >> 4;

    f32x4 acc[8][4] = {};

    int k0 = 0;
    if (bn >= 2048 && bn < 3072) k0 = 1024;  // w_i half of these rows is zero
    const int nt = (KDIM - k0) / BK;         // 32 or 16

    // Prologue: tile0 all 4 halves + tile1 {B0,A1,B1} (7 half-tiles,
    // 14 loads); vmcnt(6) forces exactly tile0's 8. tile1.A0 staged at t0.P1.
    STAGE_HALF_A(0, 0, 0); STAGE_HALF_B(0, 0, 0);
    STAGE_HALF_A(0, 1, 0); STAGE_HALF_B(0, 1, 0);
    STAGE_HALF_B(1, 0, 1); STAGE_HALF_A(1, 1, 1); STAGE_HALF_B(1, 1, 1);
    asm volatile("s_waitcnt vmcnt(6)" ::: "memory");
    PHASE_BAR();

    for (int t = 0; t < nt; ++t) {
        const int cur = t & 1;
        const int nxt = cur ^ 1;
        bf16x8 a0[4][2], a1[4][2], b0[2][2], b1[2][2];

        // P1: quadrant (m0,n0); stage (t+1).A0 into buf nxt.
        READ_A4(cur, a0, 0); READ_B2(cur, b0, 0);
        if (t + 1 < nt) STAGE_HALF_A(nxt, 0, t + 1);
        PHASE_BAR();
        MFMA_Q(0, 0, a0, b0);
        PHASE_BAR();

        // P2: quadrant (m1,n0); b0 reused from regs; stage (t+2).B0
        // (region last read in P1, one barrier earlier).
        READ_A4(cur, a1, 1);
        if (t + 2 < nt) STAGE_HALF_B(cur, 0, t + 2);
        PHASE_BAR();
        MFMA_Q(1, 0, a1, b0);
        PHASE_BAR();

        // P3: quadrant (m1,n1); a1 reused; stage (t+2).A1
        // (region last read in P2).
        READ_B2(cur, b1, 1);
        if (t + 2 < nt) STAGE_HALF_A(cur, 1, t + 2);
        PHASE_BAR();
        MFMA_Q(1, 1, a1, b1);
        PHASE_BAR();

        // P4: quadrant (m0,n1); A0 re-read (region untouched this iter);
        // b1 reused; stage (t+2).B1 (region last read in P3), then the
        // per-tile counted wait (forces all of tile t+1).
        READ_A4(cur, a0, 0);
        if (t + 2 < nt) {
            STAGE_HALF_B(cur, 1, t + 2);
            asm volatile("s_waitcnt vmcnt(6)" ::: "memory");
        } else if (t + 1 < nt) {
            asm volatile("s_waitcnt vmcnt(0)" ::: "memory");
        }
        PHASE_BAR();
        MFMA_Q(0, 1, a0, b1);
        PHASE_BAR();
    }

    // Epilogue: C/D mapping col=lane&15, row=(lane>>4)*4+reg (m89-verified).
#pragma unroll
    for (int i = 0; i < 8; ++i) {
#pragma unroll
        for (int j = 0; j < 4; ++j) {
#pragma unroll
            for (int r = 0; r < 4; ++r) {
                int row = bm + wm + i * 16 + l16 * 4 + r;
                int col = bn + wn + j * 16 + ln15;
                G[(size_t)row * NDIM + col] = f2bf(acc[i][j][r]);
            }
        }
    }
}

// ---------------------------------------------------------------------------
// Elementwise (R10): wave-per-row, pure shuffle reductions, no barriers/LDS.
// rcp-based activations (v_rcp_f32; absmax tol 0.03 >> 1ulp).
// R9: ew_full <= ~61us (never surfaced in top-5 above gemm chunks).
// G (bf16) row layout: [s0=i_i+h_i | s1=i_f+h_f | s2=h_g | s3=i_o+h_o]
// Lane l covers cols {j*512 + l*8 + e : j in 0..1, e in 0..7}.
// ---------------------------------------------------------------------------
__device__ inline float fast_rcp(float x) { return __builtin_amdgcn_rcpf(x); }
__device__ inline float sigmoid_f(float x) {
    return fast_rcp(1.f + __expf(-x));
}
// safe fast tanh: exact +/-1 saturation at both ends
__device__ inline float tanh_f(float x) {
    return 1.f - 2.f * fast_rcp(__expf(2.f * x) + 1.f);
}

__device__ inline void wstats(const float* x, float& mu, float& rs)
{
    float s = 0.f, q = 0.f;
#pragma unroll
    for (int e = 0; e < 16; ++e) { s += x[e]; q += x[e] * x[e]; }
#pragma unroll
    for (int o = 1; o < 64; o <<= 1) {
        s += __shfl_xor(s, o);
        q += __shfl_xor(q, o);
    }
    mu = s * (1.f / 1024.f);
    float var = q * (1.f / 1024.f) - mu * mu;
    rs = rsqrtf(var + 1e-5f);
}

// 16 bf16 -> fp32 per thread: two 16B ushort8 loads
#define LOADG16(dst, basep)                                            \
    _Pragma("unroll")                                                  \
    for (int j = 0; j < 2; ++j) {                                      \
        us8 t = *(const us8*)((basep) + j * 512 + cbase);              \
        _Pragma("unroll")                                              \
        for (int e = 0; e < 8; ++e) dst[j * 8 + e] = bf2f(t[e]);       \
    }

// 16 fp32 per thread (params / c_prev): four float4 loads
#define LOADF16(dst, basep)                                            \
    _Pragma("unroll")                                                  \
    for (int j = 0; j < 2; ++j) {                                      \
        float4 a = *(const float4*)((basep) + j * 512 + cbase);        \
        float4 b = *(const float4*)((basep) + j * 512 + cbase + 4);    \
        dst[j * 8 + 0] = a.x; dst[j * 8 + 1] = a.y;                    \
        dst[j * 8 + 2] = a.z; dst[j * 8 + 3] = a.w;                    \
        dst[j * 8 + 4] = b.x; dst[j * 8 + 5] = b.y;                    \
        dst[j * 8 + 6] = b.z; dst[j * 8 + 7] = b.w;                    \
    }

__global__ __launch_bounds__(256) void lstm_ew_kernel(
    const unsigned short* __restrict__ G,
    const float* __restrict__ c_prev,
    const float* __restrict__ p0g, const float* __restrict__ p0b,
    const float* __restrict__ p1g, const float* __restrict__ p1b,
    const float* __restrict__ p2g, const float* __restrict__ p2b,
    const float* __restrict__ p3g, const float* __restrict__ p3b,
    const float* __restrict__ p4g, const float* __restrict__ p4b,
    float* __restrict__ out_h, float* __restrict__ out_c,
    int row_base)
{
    const int lane  = threadIdx.x & 63;
    const int wave  = threadIdx.x >> 6;
    const int r     = blockIdx.x * 4 + wave;
    const int grow  = row_base + r;
    const int cbase = lane * 8;

    const unsigned short* Grow = G + (size_t)r * NDIM;

    float tmp[16], pg[16], pb[16];
    float ig[16], cm[16], og[16];
    float mu, rs;

    // i gate: sigmoid(LN(i_i+h_i; ln_i))
    LOADG16(tmp, Grow);
    wstats(tmp, mu, rs);
    LOADF16(pg, p0g); LOADF16(pb, p0b);
#pragma unroll
    for (int e = 0; e < 16; ++e)
        ig[e] = sigmoid_f((tmp[e] - mu) * rs * pg[e] + pb[e]);

    // f gate: sigmoid(LN(i_f+h_f; ln_h)); cm = f * c_prev
    LOADG16(tmp, Grow + 1024);
    wstats(tmp, mu, rs);
    LOADF16(pg, p1g); LOADF16(pb, p1b);
    LOADF16(cm, c_prev + (size_t)grow * HDIM);
#pragma unroll
    for (int e = 0; e < 16; ++e)
        cm[e] *= sigmoid_f((tmp[e] - mu) * rs * pg[e] + pb[e]);

    // g gate: tanh(LN(i_g + h_g; ln_g))  <- faithful bug: i_g is sigmoided gate
    LOADG16(tmp, Grow + 2048);
#pragma unroll
    for (int e = 0; e < 16; ++e) tmp[e] += ig[e];
    wstats(tmp, mu, rs);
    LOADF16(pg, p2g); LOADF16(pb, p2b);
#pragma unroll
    for (int e = 0; e < 16; ++e)
        cm[e] += ig[e] * tanh_f((tmp[e] - mu) * rs * pg[e] + pb[e]);

    // o gate: sigmoid(LN(i_o+h_o; ln_o))
    LOADG16(tmp, Grow + 3072);
    wstats(tmp, mu, rs);
    LOADF16(pg, p3g); LOADF16(pb, p3b);
#pragma unroll
    for (int e = 0; e < 16; ++e)
        og[e] = sigmoid_f((tmp[e] - mu) * rs * pg[e] + pb[e]);

    // c_new = LN(cm; ln_c); h_new = o * tanh(c_new)
    wstats(cm, mu, rs);
    LOADF16(pg, p4g); LOADF16(pb, p4b);
    float cn[16], hn[16];
#pragma unroll
    for (int e = 0; e < 16; ++e) {
        cn[e] = (cm[e] - mu) * rs * pg[e] + pb[e];
        hn[e] = og[e] * tanh_f(cn[e]);
    }

    float* oh = out_h + (size_t)grow * HDIM;
    float* oc = out_c + (size_t)grow * HDIM;
#pragma unroll
    for (int j = 0; j < 2; ++j) {
        *(float4*)(oh + j * 512 + cbase) =
            make_float4(hn[j*8+0], hn[j*8+1], hn[j*8+2], hn[j*8+3]);
        *(float4*)(oh + j * 512 + cbase + 4) =
            make_float4(hn[j*8+4], hn[j*8+5], hn[j*8+6], hn[j*8+7]);
        *(float4*)(oc + j * 512 + cbase) =
            make_float4(cn[j*8+0], cn[j*8+1], cn[j*8+2], cn[j*8+3]);
        *(float4*)(oc + j * 512 + cbase + 4) =
            make_float4(cn[j*8+4], cn[j*8+5], cn[j*8+6], cn[j*8+7]);
    }
}

extern "C" void kernel_launch(void* const* d_in, const int* in_sizes, int n_in,
                              void* d_out, int out_size, void* d_ws, size_t ws_size,
                              hipStream_t stream)
{
    const float* input  = (const float*)d_in[0];
    const float* h_prev = (const float*)d_in[1];
    const float* c_prev = (const float*)d_in[2];
    const float* w_i    = (const float*)d_in[3];
    const float* w_h    = (const float*)d_in[4];
    const float* lng[10];
    for (int i = 0; i < 10; ++i) lng[i] = (const float*)d_in[5 + i];

    // Workspace: Xb bf16 [8192,2048] | Wb bf16 [4096,2048] | G bf16 [8192,4096]
    // (117.4 MB total; proven to fit.)
    unsigned short* Xb = (unsigned short*)d_ws;
    size_t xb_bytes = (size_t)BATCH * KDIM * 2;
    unsigned short* Wb = (unsigned short*)((char*)d_ws + xb_bytes);
    size_t wb_bytes = (size_t)NDIM * KDIM * 2;
    unsigned short* G = (unsigned short*)((char*)d_ws + xb_bytes + wb_bytes);

    convert_kernel<<<(NDIM * 256 + BATCH * 256) / 256, 256, 0, stream>>>(
        w_i, w_h, input, h_prev, Wb, Xb);

    float* out_h = (float*)d_out;
    float* out_c = out_h + (size_t)BATCH * HDIM;

    // 3 launches total (launch gap ~8-9us each; R8/R9 measured).
    gemm_bt_kernel<<<(BATCH / BM) * (NDIM / BN), 512, 0, stream>>>(
        Xb, Wb, G, BATCH);
    lstm_ew_kernel<<<BATCH / 4, 256, 0, stream>>>(
        G, c_prev, lng[0], lng[1], lng[2], lng[3], lng[4],
        lng[5], lng[6], lng[7], lng[8], lng[9], out_h, out_c, 0);
}

// Round 9
// 337.925 us; speedup vs baseline: 1.0199x; 1.0199x over previous
//
#include <hip/hip_runtime.h>
#include <hip/hip_bf16.h>

// Problem constants (B=8192, IN=H=1024)
#define BATCH 8192
#define HDIM  1024
#define KDIM  2048   // IN + H concatenated
#define NDIM  4096   // 4*H

__device__ inline unsigned short f2bf(float x) {
    unsigned int u = __float_as_uint(x);
    unsigned int r = (u + 0x7fffu + ((u >> 16) & 1u)) >> 16;
    return (unsigned short)r;
}
__device__ inline float bf2f(unsigned short u) {
    return __uint_as_float((unsigned int)u << 16);
}

typedef __attribute__((ext_vector_type(8))) unsigned short us8;

// Merged converter v2: 8 elems/thread, 16B stores (full-line coalescing).
//  Wb [4096,2048] bf16: row n = [w_i[n] | w_h[n]], w_i half zeroed for rows
//  2048..3071 (chunk i_gc of gi is unused by the reference).
//  Xb [8192,2048] bf16: row r = [input[r] | h_prev[r]]
// R8/R9 localization: convert <= ~61us (never surfaced in top-5);
// roofline ~24us (150 MB @ 6.3 TB/s).
__global__ __launch_bounds__(256) void convert_kernel(
    const float* __restrict__ wi, const float* __restrict__ wh,
    const float* __restrict__ input, const float* __restrict__ h_prev,
    unsigned short* __restrict__ Wb, unsigned short* __restrict__ Xb)
{
    int idx = blockIdx.x * 256 + threadIdx.x;
    const int NW = NDIM * 256;              // weight 8-elem groups per matrix
    float4 v0, v1;
    unsigned short* dst;
    if (idx < NW) {
        int n = idx >> 8;
        int k = (idx & 255) << 3;
        if (k < 1024) {
            if (n >= 2048 && n < 3072) {
                v0 = make_float4(0.f, 0.f, 0.f, 0.f);
                v1 = v0;
            } else {
                v0 = *(const float4*)(wi + (size_t)n * 1024 + k);
                v1 = *(const float4*)(wi + (size_t)n * 1024 + k + 4);
            }
        } else {
            v0 = *(const float4*)(wh + (size_t)n * 1024 + (k - 1024));
            v1 = *(const float4*)(wh + (size_t)n * 1024 + (k - 1024) + 4);
        }
        dst = Wb + (size_t)n * KDIM + k;
    } else {
        int j = idx - NW;
        int r = j >> 8;
        int k = (j & 255) << 3;
        if (k < 1024) {
            v0 = *(const float4*)(input + (size_t)r * 1024 + k);
            v1 = *(const float4*)(input + (size_t)r * 1024 + k + 4);
        } else {
            v0 = *(const float4*)(h_prev + (size_t)r * 1024 + (k - 1024));
            v1 = *(const float4*)(h_prev + (size_t)r * 1024 + (k - 1024) + 4);
        }
        dst = Xb + (size_t)r * KDIM + k;
    }
    us8 o;
    o[0] = f2bf(v0.x); o[1] = f2bf(v0.y); o[2] = f2bf(v0.z); o[3] = f2bf(v0.w);
    o[4] = f2bf(v1.x); o[5] = f2bf(v1.y); o[6] = f2bf(v1.z); o[7] = f2bf(v1.w);
    *(us8*)dst = o;
}

// ---------------------------------------------------------------------------
// GEMM (R4, verified 121us / 994 TF effective): G[M,N](bf16) = A * Bw^T
// 256x128 tile, 512 threads (8 waves, 4m x 2n of 64x64 wave-tiles), BK=64.
// XOR-swizzled LDS k-chunks -> 0 bank conflicts. 48KB LDS -> 3 blocks/CU:
// inter-block wave overlap (m114) hides the barrier drain.
// FINAL structure decision after 3 pipeline attempts all regressed:
//   R5  256x256 2-deep dbuf coarse phases: 146us (vmcnt near-drain)
//   R6  3-deep ring 144KB: 202us (1 block/CU, no fine interleave)
//   R12 m201-style 4-phase 256x256 (race-free, verified): 142us
//       (MfmaUtil 35 @ 1 block/CU < 44 @ 3 blocks/CU)
// On this problem (K=2048, tall-M), 2-phase + 3-blocks/CU TLP wins.
// k0-skip: output cols 2048-3071 (gate g) need only the w_h half of K.
// ---------------------------------------------------------------------------
#define BM 256
#define BN 128
#define BK 64    // bf16 elems per row; 128 B

typedef __attribute__((ext_vector_type(8))) short bf16x8;
typedef __attribute__((ext_vector_type(4))) float f32x4;

__global__ __launch_bounds__(512) void gemm_bt_kernel(
    const unsigned short* __restrict__ A,
    const unsigned short* __restrict__ Bw,
    unsigned short* __restrict__ G,
    int M)
{
    __shared__ unsigned short As[BM * BK];   // 32 KB
    __shared__ unsigned short Bs[BN * BK];   // 16 KB

    const int tid  = threadIdx.x;
    const int lane = tid & 63;
    const int wave = tid >> 6;               // 0..7

    const int bid = blockIdx.x;              // n-fastest linear
    const int bm  = (bid >> 5) * BM;
    const int bn  = (bid & 31) * BN;

    f32x4 acc[4][4] = {};

    const int wm = (wave >> 1) * 64;         // 0,64,128,192
    const int wn = (wave & 1) * 64;          // 0,64

    // staging: lane l covers row (l>>3) of its 8-row group, LDS chunk (l&7).
    // XOR swizzle: LDS row r, position p holds global k-chunk p ^ (r&7).
    const int srow = lane >> 3;              // 0..7
    const int c_sw = (lane & 7) ^ srow;      // global 16B-chunk to fetch

    int k0 = 0;
    if (bn >= 2048 && bn < 3072) k0 = 1024;  // w_i half of these rows is zero

    for (; k0 < KDIM; k0 += BK) {
        // A: 4 loads/wave covering rows [wave*32, wave*32+32)
#pragma unroll
        for (int p = 0; p < 4; ++p) {
            const int rbase = wave * 32 + p * 8;
            const unsigned short* gA =
                A + (size_t)(bm + rbase + srow) * KDIM + k0 + c_sw * 8;
            __builtin_amdgcn_global_load_lds(
                (const __attribute__((address_space(1))) void*)gA,
                (__attribute__((address_space(3))) void*)&As[rbase * BK], 16, 0, 0);
        }
        // B: 2 loads/wave covering rows [wave*16, wave*16+16)
#pragma unroll
        for (int p = 0; p < 2; ++p) {
            const int rbase = wave * 16 + p * 8;
            const unsigned short* gB =
                Bw + (size_t)(bn + rbase + srow) * KDIM + k0 + c_sw * 8;
            __builtin_amdgcn_global_load_lds(
                (const __attribute__((address_space(1))) void*)gB,
                (__attribute__((address_space(3))) void*)&Bs[rbase * BK], 16, 0, 0);
        }
        __syncthreads();

#pragma unroll
        for (int kk = 0; kk < 2; ++kk) {
            bf16x8 af[4], bfr[4];
            const int cbase = kk * 4 + (lane >> 4);   // 16B-chunk index 0..7
#pragma unroll
            for (int i = 0; i < 4; ++i) {
                const int ra = wm + i * 16 + (lane & 15);
                af[i]  = *(const bf16x8*)&As[ra * BK + ((cbase ^ (ra & 7)) * 8)];
                const int rb = wn + i * 16 + (lane & 15);
                bfr[i] = *(const bf16x8*)&Bs[rb * BK + ((cbase ^ (rb & 7)) * 8)];
            }
#pragma unroll
            for (int i = 0; i < 4; ++i)
#pragma unroll
                for (int j = 0; j < 4; ++j)
                    acc[i][j] = __builtin_amdgcn_mfma_f32_16x16x32_bf16(
                        af[i], bfr[j], acc[i][j], 0, 0, 0);
        }
        __syncthreads();
    }

    // Epilogue: C/D mapping col=lane&15, row=(lane>>4)*4+reg (m89-verified).
    // bf16 stores (2B): halves G write traffic.
#pragma unroll
    for (int i = 0; i < 4; ++i) {
#pragma unroll
        for (int j = 0; j < 4; ++j) {
#pragma unroll
            for (int r = 0; r < 4; ++r) {
                int row = bm + wm + i * 16 + (lane >> 4) * 4 + r;
                int col = bn + wn + j * 16 + (lane & 15);
                G[(size_t)row * NDIM + col] = f2bf(acc[i][j][r]);
            }
        }
    }
}

// ---------------------------------------------------------------------------
// Elementwise (R10, verified): wave-per-row, pure shuffle reductions, no
// barriers/LDS; rcp-based activations (v_rcp_f32; absmax tol 0.03 >> 1ulp).
// Full TLP: 2048 blocks x 4 waves = 32 waves/CU. R9: full-batch ew <= ~61us;
// roofline ~26us (160 MB). R7's LDS-param + 4-rows/wave variant cost +9us
// (TLP loss) -- keep wave-per-row.
// G (bf16) row layout: [s0=i_i+h_i | s1=i_f+h_f | s2=h_g | s3=i_o+h_o]
// Lane l covers cols {j*512 + l*8 + e : j in 0..1, e in 0..7}.
// ---------------------------------------------------------------------------
__device__ inline float fast_rcp(float x) { return __builtin_amdgcn_rcpf(x); }
__device__ inline float sigmoid_f(float x) {
    return fast_rcp(1.f + __expf(-x));
}
// safe fast tanh: exact +/-1 saturation at both ends
__device__ inline float tanh_f(float x) {
    return 1.f - 2.f * fast_rcp(__expf(2.f * x) + 1.f);
}

__device__ inline void wstats(const float* x, float& mu, float& rs)
{
    float s = 0.f, q = 0.f;
#pragma unroll
    for (int e = 0; e < 16; ++e) { s += x[e]; q += x[e] * x[e]; }
#pragma unroll
    for (int o = 1; o < 64; o <<= 1) {
        s += __shfl_xor(s, o);
        q += __shfl_xor(q, o);
    }
    mu = s * (1.f / 1024.f);
    float var = q * (1.f / 1024.f) - mu * mu;
    rs = rsqrtf(var + 1e-5f);
}

// 16 bf16 -> fp32 per thread: two 16B ushort8 loads
#define LOADG16(dst, basep)                                            \
    _Pragma("unroll")                                                  \
    for (int j = 0; j < 2; ++j) {                                      \
        us8 t = *(const us8*)((basep) + j * 512 + cbase);              \
        _Pragma("unroll")                                              \
        for (int e = 0; e < 8; ++e) dst[j * 8 + e] = bf2f(t[e]);       \
    }

// 16 fp32 per thread (params / c_prev): four float4 loads
#define LOADF16(dst, basep)                                            \
    _Pragma("unroll")                                                  \
    for (int j = 0; j < 2; ++j) {                                      \
        float4 a = *(const float4*)((basep) + j * 512 + cbase);        \
        float4 b = *(const float4*)((basep) + j * 512 + cbase + 4);    \
        dst[j * 8 + 0] = a.x; dst[j * 8 + 1] = a.y;                    \
        dst[j * 8 + 2] = a.z; dst[j * 8 + 3] = a.w;                    \
        dst[j * 8 + 4] = b.x; dst[j * 8 + 5] = b.y;                    \
        dst[j * 8 + 6] = b.z; dst[j * 8 + 7] = b.w;                    \
    }

__global__ __launch_bounds__(256) void lstm_ew_kernel(
    const unsigned short* __restrict__ G,
    const float* __restrict__ c_prev,
    const float* __restrict__ p0g, const float* __restrict__ p0b,
    const float* __restrict__ p1g, const float* __restrict__ p1b,
    const float* __restrict__ p2g, const float* __restrict__ p2b,
    const float* __restrict__ p3g, const float* __restrict__ p3b,
    const float* __restrict__ p4g, const float* __restrict__ p4b,
    float* __restrict__ out_h, float* __restrict__ out_c,
    int row_base)
{
    const int lane  = threadIdx.x & 63;
    const int wave  = threadIdx.x >> 6;
    const int r     = blockIdx.x * 4 + wave;
    const int grow  = row_base + r;
    const int cbase = lane * 8;

    const unsigned short* Grow = G + (size_t)r * NDIM;

    float tmp[16], pg[16], pb[16];
    float ig[16], cm[16], og[16];
    float mu, rs;

    // i gate: sigmoid(LN(i_i+h_i; ln_i))
    LOADG16(tmp, Grow);
    wstats(tmp, mu, rs);
    LOADF16(pg, p0g); LOADF16(pb, p0b);
#pragma unroll
    for (int e = 0; e < 16; ++e)
        ig[e] = sigmoid_f((tmp[e] - mu) * rs * pg[e] + pb[e]);

    // f gate: sigmoid(LN(i_f+h_f; ln_h)); cm = f * c_prev
    LOADG16(tmp, Grow + 1024);
    wstats(tmp, mu, rs);
    LOADF16(pg, p1g); LOADF16(pb, p1b);
    LOADF16(cm, c_prev + (size_t)grow * HDIM);
#pragma unroll
    for (int e = 0; e < 16; ++e)
        cm[e] *= sigmoid_f((tmp[e] - mu) * rs * pg[e] + pb[e]);

    // g gate: tanh(LN(i_g + h_g; ln_g))  <- faithful bug: i_g is sigmoided gate
    LOADG16(tmp, Grow + 2048);
#pragma unroll
    for (int e = 0; e < 16; ++e) tmp[e] += ig[e];
    wstats(tmp, mu, rs);
    LOADF16(pg, p2g); LOADF16(pb, p2b);
#pragma unroll
    for (int e = 0; e < 16; ++e)
        cm[e] += ig[e] * tanh_f((tmp[e] - mu) * rs * pg[e] + pb[e]);

    // o gate: sigmoid(LN(i_o+h_o; ln_o))
    LOADG16(tmp, Grow + 3072);
    wstats(tmp, mu, rs);
    LOADF16(pg, p3g); LOADF16(pb, p3b);
#pragma unroll
    for (int e = 0; e < 16; ++e)
        og[e] = sigmoid_f((tmp[e] - mu) * rs * pg[e] + pb[e]);

    // c_new = LN(cm; ln_c); h_new = o * tanh(c_new)
    wstats(cm, mu, rs);
    LOADF16(pg, p4g); LOADF16(pb, p4b);
    float cn[16], hn[16];
#pragma unroll
    for (int e = 0; e < 16; ++e) {
        cn[e] = (cm[e] - mu) * rs * pg[e] + pb[e];
        hn[e] = og[e] * tanh_f(cn[e]);
    }

    float* oh = out_h + (size_t)grow * HDIM;
    float* oc = out_c + (size_t)grow * HDIM;
#pragma unroll
    for (int j = 0; j < 2; ++j) {
        *(float4*)(oh + j * 512 + cbase) =
            make_float4(hn[j*8+0], hn[j*8+1], hn[j*8+2], hn[j*8+3]);
        *(float4*)(oh + j * 512 + cbase + 4) =
            make_float4(hn[j*8+4], hn[j*8+5], hn[j*8+6], hn[j*8+7]);
        *(float4*)(oc + j * 512 + cbase) =
            make_float4(cn[j*8+0], cn[j*8+1], cn[j*8+2], cn[j*8+3]);
        *(float4*)(oc + j * 512 + cbase + 4) =
            make_float4(cn[j*8+4], cn[j*8+5], cn[j*8+6], cn[j*8+7]);
    }
}

extern "C" void kernel_launch(void* const* d_in, const int* in_sizes, int n_in,
                              void* d_out, int out_size, void* d_ws, size_t ws_size,
                              hipStream_t stream)
{
    const float* input  = (const float*)d_in[0];
    const float* h_prev = (const float*)d_in[1];
    const float* c_prev = (const float*)d_in[2];
    const float* w_i    = (const float*)d_in[3];
    const float* w_h    = (const float*)d_in[4];
    const float* lng[10];
    for (int i = 0; i < 10; ++i) lng[i] = (const float*)d_in[5 + i];

    // Workspace: Xb bf16 [8192,2048] | Wb bf16 [4096,2048] | G bf16 [8192,4096]
    // (117.4 MB total; proven to fit.)
    unsigned short* Xb = (unsigned short*)d_ws;
    size_t xb_bytes = (size_t)BATCH * KDIM * 2;
    unsigned short* Wb = (unsigned short*)((char*)d_ws + xb_bytes);
    size_t wb_bytes = (size_t)NDIM * KDIM * 2;
    unsigned short* G = (unsigned short*)((char*)d_ws + xb_bytes + wb_bytes);

    convert_kernel<<<(NDIM * 256 + BATCH * 256) / 256, 256, 0, stream>>>(
        w_i, w_h, input, h_prev, Wb, Xb);

    float* out_h = (float*)d_out;
    float* out_c = out_h + (size_t)BATCH * HDIM;

    // 3 launches total (launch gap ~8-9us each; R8/R9 measured).
    gemm_bt_kernel<<<(BATCH / BM) * (NDIM / BN), 512, 0, stream>>>(
        Xb, Wb, G, BATCH);
    lstm_ew_kernel<<<BATCH / 4, 256, 0, stream>>>(
        G, c_prev, lng[0], lng[1], lng[2], lng[3], lng[4],
        lng[5], lng[6], lng[7], lng[8], lng[9], out_h, out_c, 0);
}